// Round 7
// baseline (484.566 us; speedup 1.0000x reference)
//
#include <hip/hip_runtime.h>
#include <math.h>

#define B_ 2
#define L_ 1024
#define DM 256
#define NL_ 6
#define DI_ 512
#define DS_ 16
#define DC_ 4
#define NC_ 10
#define ALPHA_ 0.1f
#define LC 32
#define NCH (L_/LC)            // 32 chunks
#define NCHAIN (B_*DI_*DS_)    // 16384 chains
#define BETA_LC 0.034336838202925124f  // 0.9^32

typedef unsigned short ushort_t;
typedef __attribute__((ext_vector_type(8))) short s16x8;      // 8 bf16 (MFMA A/B frag)
typedef __attribute__((ext_vector_type(4))) float f32x4;      // MFMA C/D frag
typedef __attribute__((ext_vector_type(8))) unsigned short u16x8;

__device__ __forceinline__ float sigmoidf_(float x){ return 1.f/(1.f+__expf(-x)); }
__device__ __forceinline__ ushort_t f2bf(float f){
  union{float f;unsigned u;} c; c.f=f; unsigned u=c.u;
  return (ushort_t)((u + 0x7fffu + ((u>>16)&1u))>>16);
}
__device__ __forceinline__ float bf2f(ushort_t h){
  union{unsigned u;float f;} c; c.u = ((unsigned)h)<<16; return c.f;
}
// stagger-pad index for sx: insert 4-word gap every 128 words (bank-conflict fix)
__device__ __forceinline__ int kidx(int d){ return d + ((d>>7)<<2); }

// ---------------- embed ----------------
__global__ void k_embed(const float* __restrict__ emb, const float* __restrict__ pos,
                        const int* __restrict__ ids, float* __restrict__ h){
  int row = blockIdx.x;
  int t = row & (L_-1);
  int d = threadIdx.x;
  int v = ids[row];
  h[(size_t)row*DM + d] = emb[(size_t)v*DM + d] + pos[(size_t)t*DM + d];
}

// ---------------- fp32 -> bf16 weight conversion ----------------
__global__ void k_cvt2(const float* __restrict__ a, int na, const float* __restrict__ b2,
                       ushort_t* __restrict__ oa, ushort_t* __restrict__ ob, int ntot){
  int i = (blockIdx.x*256 + threadIdx.x)*4;
  if (i >= ntot) return;
  const float* src; ushort_t* dst; int k;
  if (i < na){ src = a; dst = oa; k = i; }
  else       { src = b2; dst = ob; k = i - na; }
  float4 v = *reinterpret_cast<const float4*>(&src[k]);
  ushort4 r;
  r.x = f2bf(v.x); r.y = f2bf(v.y); r.z = f2bf(v.z); r.w = f2bf(v.w);
  *reinterpret_cast<ushort4*>(&dst[k]) = r;
}

// ---------------- fused LN + in_proj GEMM (bf16 MFMA), writes xz bf16 ----------------
__global__ __launch_bounds__(256) void k_gemm_ln(const float* __restrict__ h,
    const ushort_t* __restrict__ W, const float* __restrict__ lw,
    const float* __restrict__ lb, ushort_t* __restrict__ xzb){
  __shared__ ushort_t As[64][264];
  __shared__ ushort_t Ws[64][264];
  int bm = blockIdx.y<<6, bn = blockIdx.x<<6;
  int tid = threadIdx.x;
  {
    int r = tid>>2, q = tid&3;
    const float* src = &h[(size_t)(bm+r)*DM + q*64];
    float4 v[16]; float s1=0.f, s2=0.f;
    #pragma unroll
    for (int i=0;i<16;i++){
      v[i] = *reinterpret_cast<const float4*>(src + i*4);
      s1 += v[i].x+v[i].y+v[i].z+v[i].w;
      s2 += v[i].x*v[i].x+v[i].y*v[i].y+v[i].z*v[i].z+v[i].w*v[i].w;
    }
    s1 += __shfl_xor(s1,1); s2 += __shfl_xor(s2,1);
    s1 += __shfl_xor(s1,2); s2 += __shfl_xor(s2,2);
    float mean = s1*(1.f/DM);
    float rstd = rsqrtf(s2*(1.f/DM) - mean*mean + 1e-5f);
    #pragma unroll
    for (int i=0;i<16;i++){
      int c = q*64 + i*4;
      ushort4 o;
      o.x = f2bf((v[i].x-mean)*rstd*lw[c+0]+lb[c+0]);
      o.y = f2bf((v[i].y-mean)*rstd*lw[c+1]+lb[c+1]);
      o.z = f2bf((v[i].z-mean)*rstd*lw[c+2]+lb[c+2]);
      o.w = f2bf((v[i].w-mean)*rstd*lw[c+3]+lb[c+3]);
      *reinterpret_cast<ushort4*>(&As[r][c]) = o;
    }
    const ushort_t* ws = &W[(size_t)(bn+r)*DM + q*64];
    #pragma unroll
    for (int i=0;i<8;i++)
      *reinterpret_cast<u16x8*>(&Ws[r][q*64+i*8]) = *reinterpret_cast<const u16x8*>(ws + i*8);
  }
  __syncthreads();
  int lane = tid&63, wid = tid>>6;
  int wm = (wid>>1)<<5, wn = (wid&1)<<5;
  int fr = lane&15, fk = (lane>>4)<<3;
  f32x4 acc[2][2] = {};
  #pragma unroll
  for (int k0=0;k0<DM;k0+=32){
    s16x8 a0 = *reinterpret_cast<const s16x8*>(&As[wm+fr][k0+fk]);
    s16x8 a1 = *reinterpret_cast<const s16x8*>(&As[wm+16+fr][k0+fk]);
    s16x8 b0 = *reinterpret_cast<const s16x8*>(&Ws[wn+fr][k0+fk]);
    s16x8 b1 = *reinterpret_cast<const s16x8*>(&Ws[wn+16+fr][k0+fk]);
    acc[0][0] = __builtin_amdgcn_mfma_f32_16x16x32_bf16(a0,b0,acc[0][0],0,0,0);
    acc[0][1] = __builtin_amdgcn_mfma_f32_16x16x32_bf16(a0,b1,acc[0][1],0,0,0);
    acc[1][0] = __builtin_amdgcn_mfma_f32_16x16x32_bf16(a1,b0,acc[1][0],0,0,0);
    acc[1][1] = __builtin_amdgcn_mfma_f32_16x16x32_bf16(a1,b1,acc[1][1],0,0,0);
  }
  int cr = (lane>>4)<<2, cc = lane&15;
  #pragma unroll
  for (int i=0;i<2;i++)
    #pragma unroll
    for (int j=0;j<2;j++){
      int row = bm + wm + (i<<4) + cr;
      int col = bn + wn + (j<<4) + cc;
      #pragma unroll
      for (int r=0;r<4;r++)
        xzb[(size_t)(row+r)*(2*DI_) + col] = f2bf(acc[i][j][r]);
    }
}

// ---------------- fused conv+SiLU + x_proj (4 rows/block) ----------------
// writes xc (bf16), xdbl (fp32, all 48 cols)
__global__ __launch_bounds__(256) void k_xpc(const ushort_t* __restrict__ xzb,
    const float* __restrict__ cw, const float* __restrict__ cb,
    const float* __restrict__ xw, ushort_t* __restrict__ xcb,
    float* __restrict__ xdbl){
  __shared__ float sxz[7][DI_];
  __shared__ float sx[4][DI_+16];    // stagger-padded: kidx(d)
  int tid = threadIdx.x;
  int m0 = blockIdx.x*4;
  // stage x-half of xz rows m0-3..m0+3 (448 u16x8 tasks)
  #pragma unroll
  for (int q=0;q<2;q++){
    int idx = q*256 + tid;
    if (idx < 448){
      int i = idx>>6, c8 = (idx&63)<<3;
      int mr = m0 - 3 + i;
      if (mr >= 0){
        u16x8 v = *reinterpret_cast<const u16x8*>(&xzb[(size_t)mr*(2*DI_) + c8]);
        #pragma unroll
        for (int e=0;e<8;e++) sxz[i][c8+e] = bf2f((ushort_t)v[e]);
      } else {
        #pragma unroll
        for (int e=0;e<8;e++) sxz[i][c8+e] = 0.f;
      }
    }
  }
  __syncthreads();
  // conv + SiLU: 256 tasks of 8 d each
  {
    int r = tid>>6, c8 = (tid&63)<<3;
    int t = (m0 + r) & (L_-1);
    u16x8 outv;
    #pragma unroll
    for (int e=0;e<8;e++){
      int d = c8 + e;
      float acc = cb[d];
      #pragma unroll
      for (int k=0;k<4;k++)
        if (t-3+k >= 0) acc = fmaf(cw[d*4+k], sxz[r+k][d], acc);
      float sv = acc * sigmoidf_(acc);
      sx[r][kidx(d)] = sv;
      outv[e] = (short)f2bf(sv);
    }
    *reinterpret_cast<u16x8*>(&xcb[(size_t)(m0+r)*DI_ + c8]) = outv;
  }
  __syncthreads();
  // x_proj: 48 outputs x 4 rows
  if (tid < 192){
    int o = tid>>2, q = tid&3;
    const float* wp = &xw[(size_t)o*DI_ + q*128];
    const int qb = q*132;
    float a0=0.f,a1=0.f,a2=0.f,a3=0.f;
    #pragma unroll 8
    for (int k4=0;k4<32;k4++){
      float4 wv = *reinterpret_cast<const float4*>(wp + k4*4);
      int kk = qb + k4*4;
      float4 x0 = *reinterpret_cast<const float4*>(&sx[0][kk]);
      float4 x1 = *reinterpret_cast<const float4*>(&sx[1][kk]);
      float4 x2 = *reinterpret_cast<const float4*>(&sx[2][kk]);
      float4 x3 = *reinterpret_cast<const float4*>(&sx[3][kk]);
      a0 = fmaf(x0.x,wv.x,a0); a0 = fmaf(x0.y,wv.y,a0); a0 = fmaf(x0.z,wv.z,a0); a0 = fmaf(x0.w,wv.w,a0);
      a1 = fmaf(x1.x,wv.x,a1); a1 = fmaf(x1.y,wv.y,a1); a1 = fmaf(x1.z,wv.z,a1); a1 = fmaf(x1.w,wv.w,a1);
      a2 = fmaf(x2.x,wv.x,a2); a2 = fmaf(x2.y,wv.y,a2); a2 = fmaf(x2.z,wv.z,a2); a2 = fmaf(x2.w,wv.w,a2);
      a3 = fmaf(x3.x,wv.x,a3); a3 = fmaf(x3.y,wv.y,a3); a3 = fmaf(x3.z,wv.z,a3); a3 = fmaf(x3.w,wv.w,a3);
    }
    a0 += __shfl_xor(a0,1); a0 += __shfl_xor(a0,2);
    a1 += __shfl_xor(a1,1); a1 += __shfl_xor(a1,2);
    a2 += __shfl_xor(a2,1); a2 += __shfl_xor(a2,2);
    a3 += __shfl_xor(a3,1); a3 += __shfl_xor(a3,2);
    if (q==0){
      xdbl[(size_t)(m0+0)*48+o]=a0;
      xdbl[(size_t)(m0+1)*48+o]=a1;
      xdbl[(size_t)(m0+2)*48+o]=a2;
      xdbl[(size_t)(m0+3)*48+o]=a3;
    }
  }
}

// ================= chunked parallel scan (LC=32) =================
// Pass A: delta on the fly + per-chunk summary {cp, hs_loc, hh_loc} (float4)
__global__ __launch_bounds__(256) void k_scanA(const ushort_t* __restrict__ xcb,
    const float* __restrict__ xdbl, const float* __restrict__ dtw,
    const float* __restrict__ dtb, const float* __restrict__ A_log,
    float4* __restrict__ smry){
  int j = blockIdx.x, g = blockIdx.y, b = blockIdx.z;
  int tid = threadIdx.x;
  int n = tid&15, dg = tid>>4;
  int d0 = g*16;
  int mbase = b*L_ + j*LC;
  __shared__ float sbd[LC][48];      // xdbl slab: [t][0..16]=dt, [16..32]=B, [32..48]=C
  __shared__ float sdtw[16][16];
  __shared__ float sxv[LC][16];
  __shared__ float sdel[LC][16];
  {
    const float4* xsrc = reinterpret_cast<const float4*>(xdbl + (size_t)mbase*48);
    reinterpret_cast<float4*>(&sbd[0][0])[tid] = xsrc[tid];
    if (tid < 128) reinterpret_cast<float4*>(&sbd[0][0])[256+tid] = xsrc[256+tid];
    if (tid < 64){
      int row = tid>>1, half = tid&1;
      u16x8 v = *reinterpret_cast<const u16x8*>(&xcb[(size_t)(mbase+row)*DI_ + d0 + half*8]);
      #pragma unroll
      for (int e=0;e<8;e++) sxv[row][half*8+e] = bf2f((ushort_t)v[e]);
    } else if (tid < 128){
      int s = tid-64, row = s>>2, c4 = (s&3)<<2;
      *reinterpret_cast<float4*>(&sdtw[row][c4]) =
        *reinterpret_cast<const float4*>(&dtw[(size_t)(d0+row)*16 + c4]);
    }
  }
  __syncthreads();
  // delta = softplus(dt @ dtw^T + dtb), 512 elems, 2 per thread
  #pragma unroll
  for (int q=0;q<2;q++){
    int p = q*256 + tid;
    int t = p>>4, dd = p&15;
    float acc = dtb[d0+dd];
    #pragma unroll
    for (int k=0;k<16;k++) acc = fmaf(sbd[t][k], sdtw[dd][k], acc);
    sdel[t][dd] = (acc>20.f)? acc : log1pf(__expf(acc));
  }
  __syncthreads();
  float a = -__expf(A_log[(d0+dg)*DS_ + n]);
  float hs=0.f, hh=0.f, cp=1.f;
  #pragma unroll
  for (int tt=0; tt<LC; tt+=8){
    float dA8[8], dBu8[8];
    #pragma unroll
    for (int t=0;t<8;t++){
      float dv = sdel[tt+t][dg];
      dA8[t]  = __expf(dv*a);
      dBu8[t] = dv * sxv[tt+t][dg] * sbd[tt+t][16+n];
    }
    #pragma unroll
    for (int t=0;t<8;t++){
      float mix = fmaf(ALPHA_, hs-hh, hh);
      hs = fmaf(dA8[t], hs, dBu8[t]);
      hh = fmaf(dA8[t], mix, dBu8[t]);
      cp *= dA8[t];
    }
  }
  smry[(size_t)j*NCHAIN + (size_t)(b*DI_+d0)*DS_ + tid] = float4{cp,hs,hh,0.f};
}

// Pass B: sequential chunk combine per chain -> per-chunk init states (float2)
__global__ __launch_bounds__(256) void k_scanB(const float4* __restrict__ smry,
    float2* __restrict__ initArr){
  int g = blockIdx.x, b = blockIdx.y;
  int c = (b*DI_ + g*16)*DS_ + threadIdx.x;
  float hs=0.f, hh=0.f;
  #pragma unroll
  for (int j=0;j<NCH;j++){
    size_t o = (size_t)j*NCHAIN + c;
    float4 v = smry[o];
    initArr[o] = float2{hs,hh};
    float snew = fmaf(v.x, hs, v.y);
    hh = fmaf(v.x, fmaf(BETA_LC, hh-hs, hs), v.z);
    hs = snew;
  }
}

// Pass C: load init, delta on the fly, re-run chunk, gate, write y2 bf16
__global__ __launch_bounds__(256) void k_scanC(const ushort_t* __restrict__ xcb,
    const float* __restrict__ xdbl, const ushort_t* __restrict__ xzb,
    const float* __restrict__ dtw, const float* __restrict__ dtb,
    const float* __restrict__ A_log, const float* __restrict__ Dp,
    const float2* __restrict__ initArr, ushort_t* __restrict__ y2b){
  int j = blockIdx.x, g = blockIdx.y, b = blockIdx.z;
  int tid = threadIdx.x;
  int n = tid&15, dg = tid>>4;
  int d0 = g*16;
  int mbase = b*L_ + j*LC;
  int chain = (b*DI_+d0)*DS_ + tid;
  float2 iv = initArr[(size_t)j*NCHAIN + chain];   // issue early
  __shared__ float sbd[LC][48];
  __shared__ float sdtw[16][16];
  __shared__ float sxv[LC][16];
  __shared__ float sdel[LC][16];
  __shared__ float sz[LC][16];
  __shared__ float sy[LC][16];
  {
    const float4* xsrc = reinterpret_cast<const float4*>(xdbl + (size_t)mbase*48);
    reinterpret_cast<float4*>(&sbd[0][0])[tid] = xsrc[tid];
    if (tid < 128) reinterpret_cast<float4*>(&sbd[0][0])[256+tid] = xsrc[256+tid];
    if (tid < 64){
      int row = tid>>1, half = tid&1;
      u16x8 v = *reinterpret_cast<const u16x8*>(&xcb[(size_t)(mbase+row)*DI_ + d0 + half*8]);
      #pragma unroll
      for (int e=0;e<8;e++) sxv[row][half*8+e] = bf2f((ushort_t)v[e]);
    } else if (tid < 128){
      int s = tid-64, row = s>>1, half = s&1;
      u16x8 v = *reinterpret_cast<const u16x8*>(&xzb[(size_t)(mbase+row)*(2*DI_) + DI_ + d0 + half*8]);
      #pragma unroll
      for (int e=0;e<8;e++) sz[row][half*8+e] = bf2f((ushort_t)v[e]);
    } else if (tid < 192){
      int s = tid-128, row = s>>2, c4 = (s&3)<<2;
      *reinterpret_cast<float4*>(&sdtw[row][c4]) =
        *reinterpret_cast<const float4*>(&dtw[(size_t)(d0+row)*16 + c4]);
    }
  }
  __syncthreads();
  #pragma unroll
  for (int q=0;q<2;q++){
    int p = q*256 + tid;
    int t = p>>4, dd = p&15;
    float acc = dtb[d0+dd];
    #pragma unroll
    for (int k=0;k<16;k++) acc = fmaf(sbd[t][k], sdtw[dd][k], acc);
    sdel[t][dd] = (acc>20.f)? acc : log1pf(__expf(acc));
  }
  __syncthreads();
  float a = -__expf(A_log[(d0+dg)*DS_ + n]);
  float hs = iv.x, hh = iv.y;
  #pragma unroll
  for (int tt=0; tt<LC; tt+=8){
    float dA8[8], dBu8[8], yv8[8];
    #pragma unroll
    for (int t=0;t<8;t++){
      float dv = sdel[tt+t][dg];
      dA8[t]  = __expf(dv*a);
      dBu8[t] = dv * sxv[tt+t][dg] * sbd[tt+t][16+n];
    }
    #pragma unroll
    for (int t=0;t<8;t++){
      float mix = fmaf(ALPHA_, hs-hh, hh);
      hs = fmaf(dA8[t], hs, dBu8[t]);
      hh = fmaf(dA8[t], mix, dBu8[t]);
      yv8[t] = hh * sbd[tt+t][32+n];
    }
    #pragma unroll
    for (int t=0;t<8;t++){
      yv8[t] += __shfl_xor(yv8[t],1,16);
      yv8[t] += __shfl_xor(yv8[t],2,16);
      yv8[t] += __shfl_xor(yv8[t],4,16);
      yv8[t] += __shfl_xor(yv8[t],8,16);
    }
    if (n==0){
      #pragma unroll
      for (int t=0;t<8;t++) sy[tt+t][dg] = yv8[t];
    }
  }
  __syncthreads();
  float dpv = Dp[d0 + (tid&15)];
  #pragma unroll
  for (int idx=0; idx<2; ++idx){
    int flat = idx*256 + tid;
    int t2 = flat>>4, dd = flat&15;
    float xvv = sxv[t2][dd];
    float zv  = sz [t2][dd];
    float yfin = (sy[t2][dd] + dpv*xvv) * (zv*sigmoidf_(zv));
    y2b[(size_t)(mbase + t2)*DI_ + d0 + dd] = f2bf(yfin);
  }
}

// ---------------- out_proj GEMM (bf16 MFMA) + residual, h += y2 @ W^T ----------------
__global__ __launch_bounds__(256) void k_gemm_out(const ushort_t* __restrict__ A,
    const ushort_t* __restrict__ W, float* __restrict__ h){
  __shared__ ushort_t As[32][264];
  __shared__ ushort_t Ws[64][264];
  int bm = blockIdx.y<<5, bn = blockIdx.x<<6;
  int tid = threadIdx.x;
  int lane = tid&63, wid = tid>>6;
  int wm = (wid>>1)<<4, wn = (wid&1)<<5;
  int fr = lane&15, fk = (lane>>4)<<3;
  f32x4 acc[2] = {};
  for (int k0=0;k0<DI_;k0+=256){
    {
      int r = tid>>3, q = tid&7;
      const ushort_t* src = &A[(size_t)(bm+r)*DI_ + k0 + q*32];
      #pragma unroll
      for (int i=0;i<4;i++)
        *reinterpret_cast<u16x8*>(&As[r][q*32+i*8]) = *reinterpret_cast<const u16x8*>(src+i*8);
      int r2 = tid>>2, q2 = tid&3;
      const ushort_t* ws = &W[(size_t)(bn+r2)*DI_ + k0 + q2*64];
      #pragma unroll
      for (int i=0;i<8;i++)
        *reinterpret_cast<u16x8*>(&Ws[r2][q2*64+i*8]) = *reinterpret_cast<const u16x8*>(ws+i*8);
    }
    __syncthreads();
    #pragma unroll
    for (int k=0;k<256;k+=32){
      s16x8 a0 = *reinterpret_cast<const s16x8*>(&As[wm+fr][k+fk]);
      s16x8 b0 = *reinterpret_cast<const s16x8*>(&Ws[wn+fr][k+fk]);
      s16x8 b1 = *reinterpret_cast<const s16x8*>(&Ws[wn+16+fr][k+fk]);
      acc[0] = __builtin_amdgcn_mfma_f32_16x16x32_bf16(a0,b0,acc[0],0,0,0);
      acc[1] = __builtin_amdgcn_mfma_f32_16x16x32_bf16(a0,b1,acc[1],0,0,0);
    }
    __syncthreads();
  }
  int cr = (lane>>4)<<2, cc = lane&15;
  #pragma unroll
  for (int jj=0;jj<2;jj++){
    int row = bm + wm + cr;
    int col = bn + wn + (jj<<4) + cc;
    #pragma unroll
    for (int r=0;r<4;r++){
      size_t idx2 = (size_t)(row+r)*DM + col;
      h[idx2] += acc[jj][r];
    }
  }
}

// ---------------- masked pooling ----------------
__global__ __launch_bounds__(256) void k_pool(const float* __restrict__ h,
    const int* __restrict__ mask, float* __restrict__ partial){
  int p = blockIdx.x, b = blockIdx.y, d = threadIdx.x;
  int t0 = p*64;
  __shared__ float sm[64];
  if (d < 64) sm[d] = (float)mask[b*L_ + t0 + d];
  __syncthreads();
  const float* hp = &h[(size_t)(b*L_ + t0)*DM + d];
  float s = 0.f;
  #pragma unroll 8
  for (int i=0;i<64;i++)
    s = fmaf(sm[i], hp[(size_t)i*DM], s);
  partial[(size_t)(b*16+p)*DM + d] = s;
}

// ---------------- final: count + LN + classifier ----------------
__global__ __launch_bounds__(256) void k_head(const float* __restrict__ partial,
    const int* __restrict__ mask, const float* __restrict__ nw, const float* __restrict__ nb,
    const float* __restrict__ cw, const float* __restrict__ cb, float* __restrict__ out){
  int b = blockIdx.x, d = threadIdx.x;
  int4 mi = *reinterpret_cast<const int4*>(&mask[b*L_ + d*4]);
  float cnt = (float)(mi.x + mi.y + mi.z + mi.w);
  #pragma unroll
  for (int o=32;o>0;o>>=1) cnt += __shfl_down(cnt,o);
  __shared__ float ac[4];
  __shared__ float scnt;
  int wid = d>>6, lane = d&63;
  if (lane==0) ac[wid] = cnt;
  __syncthreads();
  if (d==0) scnt = ac[0]+ac[1]+ac[2]+ac[3];
  __syncthreads();
  float s = 0.f;
  #pragma unroll
  for (int p=0;p<16;p++) s += partial[(size_t)(b*16+p)*DM + d];
  float v = s / scnt;
  float s1 = v, s2 = v*v;
  #pragma unroll
  for (int o=32;o>0;o>>=1){ s1 += __shfl_down(s1,o); s2 += __shfl_down(s2,o); }
  __shared__ float a1[4], a2[4];
  __shared__ float mv[2];
  if (lane==0){ a1[wid]=s1; a2[wid]=s2; }
  __syncthreads();
  if (d==0){
    float t1=a1[0]+a1[1]+a1[2]+a1[3];
    float t2=a2[0]+a2[1]+a2[2]+a2[3];
    float m = t1/(float)DM;
    mv[0]=m; mv[1]=rsqrtf(t2/(float)DM - m*m + 1e-5f);
  }
  __syncthreads();
  __shared__ float sp[DM];
  sp[d] = (v-mv[0])*mv[1]*nw[d]+nb[d];
  __syncthreads();
  __shared__ float cpart[NC_][16];
  if (d < NC_*16){
    int c = d>>4, q = d&15;
    float acc = 0.f;
    #pragma unroll
    for (int k=0;k<16;k++) acc = fmaf(sp[q*16+k], cw[(size_t)c*DM+q*16+k], acc);
    cpart[c][q] = acc;
  }
  __syncthreads();
  if (d < NC_){
    float acc = cb[d];
    #pragma unroll
    for (int q=0;q<16;q++) acc += cpart[d][q];
    out[b*NC_+d] = acc;
  }
}

extern "C" void kernel_launch(void* const* d_in, const int* in_sizes, int n_in,
                              void* d_out, int out_size, void* d_ws, size_t ws_size,
                              hipStream_t stream){
  const float* emb   = (const float*)d_in[0];
  const float* pos   = (const float*)d_in[1];
  const float* ln_w  = (const float*)d_in[2];
  const float* ln_b  = (const float*)d_in[3];
  const float* ipw   = (const float*)d_in[4];
  const float* cw    = (const float*)d_in[5];
  const float* cb    = (const float*)d_in[6];
  const float* xpw   = (const float*)d_in[7];
  const float* dtw   = (const float*)d_in[8];
  const float* dtb   = (const float*)d_in[9];
  const float* A_log = (const float*)d_in[10];
  const float* Dp    = (const float*)d_in[11];
  const float* opw   = (const float*)d_in[12];
  const float* nw    = (const float*)d_in[13];
  const float* nb    = (const float*)d_in[14];
  const float* clw   = (const float*)d_in[15];
  const float* clb   = (const float*)d_in[16];
  const int*   ids   = (const int*)d_in[17];
  const int*   mask  = (const int*)d_in[18];
  float* out = (float*)d_out;

  float* ws    = (float*)d_ws;
  float* h     = ws;                     // 524288 floats
  float* xdbl  = h + 524288;             // 98304
  float* part  = xdbl + 98304;           // 8192
  float4* smry = (float4*)(part + 8192); // 524288 float4 = 2097152 floats
  float2* initA= (float2*)((float*)smry + 2097152); // 524288 float2 = 1048576 floats
  ushort_t* xzb  = (ushort_t*)((float*)initA + 1048576); // 2048*1024
  ushort_t* xcb  = xzb + 2097152;        // 2048*512
  ushort_t* y2b  = xcb + 1048576;        // 2048*512
  ushort_t* ipwb = y2b + 1048576;        // 6*1024*256
  ushort_t* opwb = ipwb + 1572864;       // 6*256*512

  const int NA = 6*2*DI_*DM, NB = 6*DM*DI_;
  k_cvt2<<<dim3((NA+NB)/1024), 256, 0, stream>>>(ipw, NA, opw, ipwb, opwb, NA+NB);
  k_embed<<<dim3(B_*L_), dim3(DM), 0, stream>>>(emb, pos, ids, h);

  for (int l=0; l<NL_; ++l){
    k_gemm_ln<<<dim3(16, 32), 256, 0, stream>>>(
        h, ipwb + (size_t)l*2*DI_*DM, ln_w + l*DM, ln_b + l*DM, xzb);
    k_xpc<<<dim3((B_*L_)/4), 256, 0, stream>>>(
        xzb, cw + l*DI_*DC_, cb + l*DI_, xpw + (size_t)l*48*DI_, xcb, xdbl);
    k_scanA<<<dim3(NCH, DI_/16, B_), 256, 0, stream>>>(
        xcb, xdbl, dtw + (size_t)l*DI_*16, dtb + l*DI_,
        A_log + (size_t)l*DI_*DS_, smry);
    k_scanB<<<dim3(DI_/16, B_), 256, 0, stream>>>(smry, initA);
    k_scanC<<<dim3(NCH, DI_/16, B_), 256, 0, stream>>>(
        xcb, xdbl, xzb, dtw + (size_t)l*DI_*16, dtb + l*DI_,
        A_log + (size_t)l*DI_*DS_, Dp + l*DI_, initA, y2b);
    k_gemm_out<<<dim3(DM/64, (B_*L_)/32), 256, 0, stream>>>(
        y2b, opwb + (size_t)l*DM*DI_, h);
  }
  k_pool<<<dim3(16, B_), 256, 0, stream>>>(h, mask, part);
  k_head<<<dim3(B_), 256, 0, stream>>>(part, mask, nw, nb, clw, clb, out);
}